// Round 16
// baseline (164.474 us; speedup 1.0000x reference)
//
#include <hip/hip_runtime.h>
#include <stdint.h>

typedef unsigned short u16;
typedef unsigned int u32;
using f32x4 = __attribute__((ext_vector_type(4))) float;
using bf16x8 = __attribute__((ext_vector_type(8))) short;
using u16x8 = __attribute__((ext_vector_type(8))) unsigned short;
using u16x4 = __attribute__((ext_vector_type(4))) unsigned short;
using u32x2 = __attribute__((ext_vector_type(2))) unsigned int;

#define QSCALE 0.18033688f  // 0.125 * log2(e): scores in exp2 domain (folded into Wq rows)

__device__ __forceinline__ u16 f2bf(float f) {
  u32 u = __float_as_uint(f);
  u32 r = (u + 0x7FFFu + ((u >> 16) & 1u)) >> 16;  // RNE
  return (u16)r;
}
__device__ __forceinline__ float bf2f(u16 h) { return __uint_as_float(((u32)h) << 16); }

// bare v_exp_f32 (2^x). Inputs are bounded (|S| < ~4) so libm's range guards are dead
// weight; builtin (NOT inline asm) keeps hazard handling compiler-owned.
__device__ __forceinline__ float fexp2(float x) { return __builtin_amdgcn_exp2f(x); }

// truncation-pack two f32 -> packed bf16 pair via one v_perm_b32. Truncation bias
// cancelled by MFMA-computed softmax denominator over the SAME values.
__device__ __forceinline__ u32 pack_trunc(float lo, float hi) {
  return __builtin_amdgcn_perm(__float_as_uint(hi), __float_as_uint(lo), 0x07060302u);
}

__device__ __forceinline__ void gload16(const void* g, void* l) {
  __builtin_amdgcn_global_load_lds((const __attribute__((address_space(1))) void*)g,
                                   (__attribute__((address_space(3))) void*)l, 16, 0, 0);
}

// ---------------- fp32 -> bf16 convert, 3 tensors; first n4sb float4s of tensor b
// scaled by QSCALE (Wq = rows [0,768) of w_qkv = 768*768 floats = 147456 float4s) ------
__global__ __launch_bounds__(256) void cvt3_kernel(const float* __restrict__ a, u16* __restrict__ da, int n4a,
                                                   const float* __restrict__ b, u16* __restrict__ db, int n4b,
                                                   const float* __restrict__ c, u16* __restrict__ dc, int n4c,
                                                   int n4sb) {
  int i = blockIdx.x * 256 + threadIdx.x;
  const float* src;
  u16* dst;
  int n;
  float s = 1.0f;
  if (i < n4a) {
    src = a; dst = da; n = i;
  } else if (i < n4a + n4b) {
    src = b; dst = db; n = i - n4a;
    if (n < n4sb) s = QSCALE;
  } else if (i < n4a + n4b + n4c) {
    src = c; dst = dc; n = i - n4a - n4b;
  } else {
    return;
  }
  const float4 f = ((const float4*)src)[n];
  u16x4 o;
  o[0] = f2bf(f.x * s); o[1] = f2bf(f.y * s); o[2] = f2bf(f.z * s); o[3] = f2bf(f.w * s);
  ((u16x4*)dst)[n] = o;
}

// ---------------- 128x128 bf16 GEMM, C = A * B^T, 2-phase double-buffered ----------------
// 512 threads / 8 waves per block, per-wave 64x32 output (wm=(wid>>2)*64, wn=(wid&3)*32,
// acc[4][2] = 32 VGPR): halves per-wave register footprint -> more resident waves/CU so
// other blocks' MFMAs fill this block's barrier drain (m114 cross-block overlap).
// Same 32KB LDS, same 2-barrier skeleton, same sw(r)=(r>>1)&3 both-sides chunk swizzle
// (bank-conflict-free, verified SQ_LDS_BANK_CONFLICT=0 in round 15).
// MODE 0: epilogue scatters qkv into q[B,H,N,64] (q pre-scaled via Wq), k[B,H,N,64], vT[B,H,64,N]
// MODE 1: epilogue writes fp32 out[M][N] += bias[n]; grid.x=136: [0,128) body+interact,
//   [128,136) head block-0-per-b which also broadcasts row 9 (vmean-proj) to rows 128..1023.
template <int MODE, int Mdim, int Ndim, int Kdim>
__global__ __launch_bounds__(512) void gemm_bt(const u16* __restrict__ A, const u16* __restrict__ Bw,
                                               u16* __restrict__ qb, u16* __restrict__ kb,
                                               u16* __restrict__ vTb,
                                               float* __restrict__ out, const float* __restrict__ bias) {
  __shared__ __align__(16) u16 lA[2][128 * 32];
  __shared__ __align__(16) u16 lB[2][128 * 32];
  __shared__ __align__(16) float bb[128];  // MODE-1 head-block broadcast row
  const int tid = threadIdx.x;
  const int wid = tid >> 6, lane = tid & 63;
  int m0;
  if constexpr (MODE == 1) {
    const int mb = blockIdx.x;
    m0 = (mb < 128) ? (8192 + mb * 128) : ((mb - 128) * 1024);
  } else {
    m0 = blockIdx.x * 128;
  }
  const int n0 = blockIdx.y * 128;
  const int wm = (wid >> 2) * 64, wn = (wid & 3) * 32;
  const int g = lane >> 4, r16 = lane & 15;

  f32x4 acc[4][2] = {};

  // staging: wave w covers rows w*16..w*16+15; lane l -> row w*16+(l>>2), LDS slot l&3.
  const int srow = wid * 16 + (lane >> 2);
  // pre-swizzled source chunk: LDS slot s=lane&3 of row srow receives global chunk s^sw(srow)
  const int scol = ((lane & 3) ^ ((srow >> 1) & 3)) * 8;
  const u16* gA = A + (size_t)(m0 + srow) * Kdim + scol;
  const u16* gB = Bw + (size_t)(n0 + srow) * Kdim + scol;

  // prologue: stage k0=0 into buffer 0 (1 gload16 per matrix per wave)
  gload16(gA, lA[0] + wid * 512);
  gload16(gB, lB[0] + wid * 512);
  __syncthreads();  // implicit vmcnt(0) drain

  int cur = 0;
  for (int k0 = 0; k0 < Kdim; k0 += 32) {
    if (k0 + 32 < Kdim) {  // prefetch next K-tile into the other buffer
      const int nk = k0 + 32;
      gload16(gA + nk, lA[cur ^ 1] + wid * 512);
      gload16(gB + nk, lB[cur ^ 1] + wid * 512);
    }
    const u16* lAc = lA[cur];
    const u16* lBc = lB[cur];
    bf16x8 af[4], bfr[2];
#pragma unroll
    for (int i = 0; i < 4; ++i) {
      const int R = wm + i * 16 + r16;
      af[i] = *(const bf16x8*)(lAc + R * 32 + ((g ^ ((R >> 1) & 3)) * 8));
    }
#pragma unroll
    for (int j = 0; j < 2; ++j) {
      const int R = wn + j * 16 + r16;
      bfr[j] = *(const bf16x8*)(lBc + R * 32 + ((g ^ ((R >> 1) & 3)) * 8));
    }
#pragma unroll
    for (int i = 0; i < 4; ++i)
#pragma unroll
      for (int j = 0; j < 2; ++j)
        acc[i][j] = __builtin_amdgcn_mfma_f32_16x16x32_bf16(af[i], bfr[j], acc[i][j], 0, 0, 0);
    __syncthreads();  // drains this iter's prefetch + all waves' ds_reads of cur
    cur ^= 1;
  }

#pragma unroll
  for (int i = 0; i < 4; ++i) {
    const int gm = m0 + wm + i * 16 + g * 4;  // multiple of 4
#pragma unroll
    for (int j = 0; j < 2; ++j) {
      const int gn = n0 + wn + j * 16 + r16;
      if constexpr (MODE == 1) {
        const float bv = bias[gn];
#pragma unroll
        for (int r = 0; r < 4; ++r) out[(size_t)(gm + r) * Ndim + gn] = acc[i][j][r] + bv;
      } else {
        const int t = gn / 768;
        const int rem = gn - t * 768;
        const int h = rem >> 6, d = rem & 63;
        if (t == 2) {
          // vT[b*12+h][d][n], 4 consecutive n -> one 8B store
          u16x4 pk;
#pragma unroll
          for (int r = 0; r < 4; ++r) pk[r] = f2bf(acc[i][j][r]);
          const int b = gm >> 10, n = gm & 1023;
          *(u16x4*)(vTb + ((size_t)((b * 12 + h) * 64 + d)) * 1024 + n) = pk;
        } else {
          u16* dst = (t == 0) ? qb : kb;
#pragma unroll
          for (int r = 0; r < 4; ++r) {
            const int b = (gm + r) >> 10, n = (gm + r) & 1023;
            dst[((size_t)((b * 12 + h) * 1024 + n)) * 64 + d] = f2bf(acc[i][j][r]);
          }
        }
      }
    }
  }

  if constexpr (MODE == 1) {
    // head blocks: broadcast row b*1024+9 (vmean projection) to rows 128..1023.
    // Row 9 = wm 0 (wid<4), i=0, g=2, r=1; value acc[0][j][1] + bias.
    if (blockIdx.x >= 128) {
      if (wid < 4 && g == 2) {
#pragma unroll
        for (int j = 0; j < 2; ++j) {
          const int col = wn + j * 16 + r16;
          bb[col] = acc[0][j][1] + bias[n0 + col];
        }
      }
      __syncthreads();  // block-uniform branch: all 512 threads participate
      const int b = blockIdx.x - 128;
      const float4 v = *(const float4*)&bb[(tid & 31) * 4];
      float* dst0 = out + (size_t)(b * 1024 + 128 + (tid >> 5)) * 768 + n0 + (tid & 31) * 4;
#pragma unroll 4
      for (int rr = 0; rr < 896; rr += 16)
        *(float4*)(dst0 + (size_t)rr * 768) = v;
    }
  }
}

// ---------------- per-(b,h) mean of v over tokens ----------------
__global__ __launch_bounds__(256) void vmean_kernel(const u16* __restrict__ vTb,
                                                    float* __restrict__ vmean) {
  const int bh = blockIdx.x, t = threadIdx.x;
  const int d = t >> 2, part = t & 3;
  const u16* src = vTb + ((size_t)bh * 64 + d) * 1024 + part * 256;
  float s = 0.f;
  for (int j = 0; j < 256; j += 8) {
    u16x8 u = *(const u16x8*)(src + j);
#pragma unroll
    for (int e = 0; e < 8; ++e) s += bf2f(u[e]);
  }
  s += __shfl_xor(s, 1);
  s += __shfl_xor(s, 2);
  if (part == 0) vmean[bh * 64 + d] = s * (1.0f / 1024.0f);
}

// ---------------- main body-branch attention (also computes interact rows 0..8) ----------
// ROUND-7 PROVEN SYNC SKELETON with TWO 64-row Q-groups per staged K/V chunk (round 13:
// stage+barrier complex amortized 2x; bk/bv fragments read once, used by both groups).
// Grid 768 = 3 blocks/CU. Swapped QK^T: S' = mfma(K_frag, Q_frag) -> S'[key][query];
// P truncation-packed (1 v_perm_b32/pair) into row-major P[query][key] (144B stride);
// PV A-frag = plain ds_read_b128; softmax denominator via ones-row MFMA over the SAME P.
__global__ __launch_bounds__(256) void body_attn(const u16* __restrict__ qg, const u16* __restrict__ kg,
                                                 const u16* __restrict__ vg, const float* __restrict__ vmean,
                                                 u16* __restrict__ og) {
  __shared__ __align__(16) u16 lK[2][64 * 64];   // [key][hd], 16B chunks XOR-swizzled by key&7
  __shared__ __align__(16) u16 lV[2][64 * 64];   // [d][tok64], 16B chunks XOR-swizzled by d&7
  __shared__ __align__(16) u16 lPA[4][16 * 72];  // per-wave P (group A), 144B row stride
  __shared__ __align__(16) u16 lPB[4][16 * 72];  // per-wave P (group B)

  const int blk = blockIdx.x;
  const int gid = (blk & 7) * 96 + (blk >> 3);  // XCD-chunked (768 % 8 == 0: bijective)
  const int rt2 = gid & 7, bh = gid >> 3;
  const int tid = threadIdx.x, wid = tid >> 6, lane = tid & 63;
  const int g = lane >> 4, r16 = lane & 15;
  const int rowA = rt2 * 128 + wid * 16;
  const int rowB = rowA + 64;

  const u16* qrowA = qg + ((size_t)bh * 1024 + rowA + r16) * 64;
  const u16* qrowB = qg + ((size_t)bh * 1024 + rowB + r16) * 64;
  const bf16x8 aqA0 = *(const bf16x8*)(qrowA + g * 8);
  const bf16x8 aqA1 = *(const bf16x8*)(qrowA + 32 + g * 8);
  const bf16x8 aqB0 = *(const bf16x8*)(qrowB + g * 8);
  const bf16x8 aqB1 = *(const bf16x8*)(qrowB + 32 + g * 8);

  const int lrow = lane >> 3, lch = lane & 7;
  const int swz = (lch ^ lrow) * 8;
  const int j0 = wid * 2;
  const u16* gK = kg + (size_t)bh * 65536 + (size_t)(j0 * 8 + lrow) * 64 + swz;
  const u16* gV = vg + (size_t)bh * 65536 + (size_t)(j0 * 8 + lrow) * 1024 + swz;

  f32x4 oaA[4] = {}, oaB[4] = {};
  f32x4 osumA = {}, osumB = {};
  u16* lPAw = lPA[wid];
  u16* lPBw = lPB[wid];

  bf16x8 vones;
#pragma unroll
  for (int i = 0; i < 8; ++i) vones[i] = (short)0x3F80;  // bf16 1.0

  auto stage = [&](int c0, int buf) {
    gload16(gK + (size_t)c0 * 64, lK[buf] + j0 * 512);
    gload16(gK + (size_t)c0 * 64 + 512, lK[buf] + (j0 + 1) * 512);
    gload16(gV + c0, lV[buf] + j0 * 512);
    gload16(gV + c0 + 8192, lV[buf] + (j0 + 1) * 512);
  };

  auto compute = [&](const u16* lKc, const u16* lVc, int c0) {
#pragma unroll
    for (int kt = 0; kt < 4; ++kt) {
      const int key = kt * 16 + r16;
      const bf16x8 bk0 = *(const bf16x8*)(lKc + key * 64 + ((g ^ (key & 7)) * 8));
      const bf16x8 bk1 = *(const bf16x8*)(lKc + key * 64 + (((4 + g) ^ (key & 7)) * 8));
      f32x4 SA = {}, SB = {};
      SA = __builtin_amdgcn_mfma_f32_16x16x32_bf16(bk0, aqA0, SA, 0, 0, 0);  // S'[key][query]
      SA = __builtin_amdgcn_mfma_f32_16x16x32_bf16(bk1, aqA1, SA, 0, 0, 0);
      SB = __builtin_amdgcn_mfma_f32_16x16x32_bf16(bk0, aqB0, SB, 0, 0, 0);
      SB = __builtin_amdgcn_mfma_f32_16x16x32_bf16(bk1, aqB1, SB, 0, 0, 0);
      float pA[4], pB[4];
#pragma unroll
      for (int r = 0; r < 4; ++r) { pA[r] = fexp2(SA[r]); pB[r] = fexp2(SB[r]); }
      if (c0 == 0 && kt == 0) {
        const int qA = rowA + r16;
        const bool dropA = (qA >= 1 && qA <= 8);  // interact rows 1..8: keys >= 9 only
#pragma unroll
        for (int r = 0; r < 4; ++r) {
          const int k = 4 * g + r;
          pA[r] = ((k >= 9) || (k == 0 && !dropA)) ? pA[r] : 0.f;
          pB[r] = ((k >= 9) || (k == 0)) ? pB[r] : 0.f;  // rowB >= 64: never drops k0
        }
      }
      u32x2 wA, wB;
      wA[0] = pack_trunc(pA[0], pA[1]);
      wA[1] = pack_trunc(pA[2], pA[3]);
      wB[0] = pack_trunc(pB[0], pB[1]);
      wB[1] = pack_trunc(pB[2], pB[3]);
      *(u32x2*)((char*)lPAw + r16 * 144 + kt * 32 + g * 8) = wA;
      *(u32x2*)((char*)lPBw + r16 * 144 + kt * 32 + g * 8) = wB;
    }
#pragma unroll
    for (int m = 0; m < 2; ++m) {
      const bf16x8 apA = *(const bf16x8*)((char*)lPAw + r16 * 144 + m * 64 + g * 16);
      const bf16x8 apB = *(const bf16x8*)((char*)lPBw + r16 * 144 + m * 64 + g * 16);
#pragma unroll
      for (int jt = 0; jt < 4; ++jt) {
        const int d = jt * 16 + r16;
        const bf16x8 bv = *(const bf16x8*)(lVc + d * 64 + (((m * 4 + g) ^ (d & 7)) * 8));
        oaA[jt] = __builtin_amdgcn_mfma_f32_16x16x32_bf16(apA, bv, oaA[jt], 0, 0, 0);
        oaB[jt] = __builtin_amdgcn_mfma_f32_16x16x32_bf16(apB, bv, oaB[jt], 0, 0, 0);
      }
      osumA = __builtin_amdgcn_mfma_f32_16x16x32_bf16(apA, vones, osumA, 0, 0, 0);
      osumB = __builtin_amdgcn_mfma_f32_16x16x32_bf16(apB, vones, osumB, 0, 0, 0);
    }
  };

  // prologue: stage chunk 0 into buffer 0
  stage(0, 0);
  __syncthreads();

  for (int it = 0; it < 8; ++it) {
    const int c0 = it * 128;
    stage(c0 + 64, 1);               // prefetch odd chunk into buf1
    compute(lK[0], lV[0], c0);
    __syncthreads();                 // buf1 ready; buf0 free
    if (it < 7) stage(c0 + 128, 0);  // prefetch next even chunk into buf0
    compute(lK[1], lV[1], c0 + 64);
    __syncthreads();                 // buf0 ready; buf1 free
  }

  const int b = bh / 12, h = bh - b * 12;
#pragma unroll
  for (int r = 0; r < 4; ++r) {
    // group A
    {
      const int grow = rowA + 4 * g + r;
      const bool full = (grow >= 1 && grow <= 8);
      const float inv = 1.f / osumA[r];
#pragma unroll
      for (int jt = 0; jt < 4; ++jt) {
        const int d = jt * 16 + r16;
        const float vi = oaA[jt][r] * inv;
        const float vb = full ? vmean[bh * 64 + d] : vi;
        og[((size_t)(8192 + b * 1024 + grow)) * 768 + h * 64 + d] = f2bf(vb);
        if (grow <= 8)  // interact rows 0..8 (only rt2==0, wid 0 reaches here)
          og[((size_t)(16384 + b * 1024 + grow)) * 768 + h * 64 + d] = f2bf(vi);
      }
    }
    // group B (rows >= 64: never "full", never interact-special)
    {
      const int grow = rowB + 4 * g + r;
      const float inv = 1.f / osumB[r];
#pragma unroll
      for (int jt = 0; jt < 4; ++jt) {
        const int d = jt * 16 + r16;
        og[((size_t)(8192 + b * 1024 + grow)) * 768 + h * 64 + d] = f2bf(oaB[jt][r] * inv);
      }
    }
  }
}

// ---------------- small branches (E path only) ----------------
// queries = 64 rows/block over all 1024 rows, keys [0,16) masked k<9.
//   grow < 9 : head rows 0..8 (computed)
//   grow >= 9: interact rows>=9 (computed) + head rows>=9 (vmean fill)
__global__ __launch_bounds__(256) void smalls_attn(const u16* __restrict__ qg, const u16* __restrict__ kg,
                                                   const u16* __restrict__ vg, const float* __restrict__ vmean,
                                                   u16* __restrict__ og) {
  __shared__ __align__(16) u16 lP2[4][16 * 40];  // per-wave P[query][key 0..31], 80B stride
  __shared__ float lsRed[4][16];
  const int bh = blockIdx.y;
  const int b = bh / 12, h = bh - b * 12;
  const int tid = threadIdx.x, wid = tid >> 6, lane = tid & 63;
  const int g = lane >> 4, r16 = lane & 15;
  u16* lPw = lP2[wid];

  const int row0 = blockIdx.x * 64 + wid * 16;
  const u16* qrow = qg + ((size_t)bh * 1024 + row0 + r16) * 64;
  const bf16x8 aq0 = *(const bf16x8*)(qrow + g * 8);
  const bf16x8 aq1 = *(const bf16x8*)(qrow + 32 + g * 8);
  const u16* krow = kg + ((size_t)bh * 1024 + r16) * 64;  // keys 0..15
  const bf16x8 bk0 = *(const bf16x8*)(krow + g * 8);
  const bf16x8 bk1 = *(const bf16x8*)(krow + 32 + g * 8);
  f32x4 S = {};
  S = __builtin_amdgcn_mfma_f32_16x16x32_bf16(bk0, aq0, S, 0, 0, 0);  // S'[key][query]
  S = __builtin_amdgcn_mfma_f32_16x16x32_bf16(bk1, aq1, S, 0, 0, 0);
  float p[4];
  float lsum = 0.f;
#pragma unroll
  for (int r = 0; r < 4; ++r) {
    const int k = 4 * g + r;
    p[r] = (k < 9) ? fexp2(S[r]) : 0.f;
    lsum += p[r];
  }
  {
    u16x4 pk;
#pragma unroll
    for (int r = 0; r < 4; ++r) pk[r] = f2bf(p[r]);
    *(u16x4*)((char*)lPw + r16 * 80 + g * 8) = pk;
    u16x4 z = {0, 0, 0, 0};
    *(u16x4*)((char*)lPw + r16 * 80 + 32 + g * 8) = z;  // keys 16..31 = 0
  }
  lsum += __shfl_xor(lsum, 16);
  lsum += __shfl_xor(lsum, 32);
  if (lane < 16) lsRed[wid][lane] = lsum;
  const bf16x8 ap = *(const bf16x8*)((char*)lPw + r16 * 80 + g * 16);
  f32x4 oa[4] = {};
#pragma unroll
  for (int jt = 0; jt < 4; ++jt) {
    const u16* vrow = vg + ((size_t)bh * 64 + jt * 16 + r16) * 1024;  // tokens 0..31
    const bf16x8 bv = *(const bf16x8*)(vrow + g * 8);
    oa[jt] = __builtin_amdgcn_mfma_f32_16x16x32_bf16(ap, bv, oa[jt], 0, 0, 0);
  }
#pragma unroll
  for (int r = 0; r < 4; ++r) {
    const int grow = row0 + 4 * g + r;
    const float inv = 1.f / lsRed[wid][4 * g + r];
#pragma unroll
    for (int jt = 0; jt < 4; ++jt) {
      const int d = jt * 16 + r16;
      const float v = oa[jt][r] * inv;
      if (grow >= 9) {
        og[((size_t)(16384 + b * 1024 + grow)) * 768 + h * 64 + d] = f2bf(v);          // interact
        og[((size_t)(b * 1024 + grow)) * 768 + h * 64 + d] = f2bf(vmean[bh * 64 + d]); // head fill
      } else {
        og[((size_t)(b * 1024 + grow)) * 768 + h * 64 + d] = f2bf(v);                  // head 0..8
      }
    }
  }
}

// ---------------- host launcher ----------------
extern "C" void kernel_launch(void* const* d_in, const int* in_sizes, int n_in,
                              void* d_out, int out_size, void* d_ws, size_t ws_size,
                              hipStream_t stream) {
  (void)in_sizes; (void)n_in; (void)out_size; (void)ws_size;
  const float* x      = (const float*)d_in[0];
  const float* w_qkv  = (const float*)d_in[1];
  const float* w_proj = (const float*)d_in[2];
  const float* b_proj = (const float*)d_in[3];

  char* ws = (char*)d_ws;
  u16* xb     = (u16*)(ws + 0);
  u16* wqkvb  = (u16*)(ws + 12582912);
  u16* wprojb = (u16*)(ws + 16121856);
  u16* qb     = (u16*)(ws + 17301504);
  u16* kb     = (u16*)(ws + 29884416);
  u16* vTb    = (u16*)(ws + 42467328);
  float* vmn  = (float*)(ws + 55050240);
  u16* ob     = (u16*)(ws + 55074816);

  // Wq = rows [0,768) of w_qkv = 768*768 floats = 147456 float4s: pre-scaled by QSCALE.
  cvt3_kernel<<<8449, 256, 0, stream>>>(x, xb, 1572864, w_qkv, wqkvb, 442368,
                                        w_proj, wprojb, 147456, 147456);

  gemm_bt<0, 8192, 2304, 768><<<dim3(64, 18), 512, 0, stream>>>(
      xb, wqkvb, qb, kb, vTb, nullptr, nullptr);

  vmean_kernel<<<96, 256, 0, stream>>>(vTb, vmn);

  body_attn<<<768, 256, 0, stream>>>(qb, kb, vTb, vmn, ob);
  smalls_attn<<<dim3(16, 96), 256, 0, stream>>>(qb, kb, vTb, vmn, ob);

  gemm_bt<1, 24576, 768, 768><<<dim3(136, 6), 512, 0, stream>>>(
      ob, wprojb, nullptr, nullptr, nullptr, (float*)d_out, b_proj);
}

// Round 17
// 158.639 us; speedup vs baseline: 1.0368x; 1.0368x over previous
//
#include <hip/hip_runtime.h>
#include <stdint.h>

typedef unsigned short u16;
typedef unsigned int u32;
using f32x4 = __attribute__((ext_vector_type(4))) float;
using bf16x8 = __attribute__((ext_vector_type(8))) short;
using u16x8 = __attribute__((ext_vector_type(8))) unsigned short;
using u16x4 = __attribute__((ext_vector_type(4))) unsigned short;
using u32x2 = __attribute__((ext_vector_type(2))) unsigned int;

#define QSCALE 0.18033688f  // 0.125 * log2(e): scores in exp2 domain (folded into Wq rows)

__device__ __forceinline__ u16 f2bf(float f) {
  u32 u = __float_as_uint(f);
  u32 r = (u + 0x7FFFu + ((u >> 16) & 1u)) >> 16;  // RNE
  return (u16)r;
}
__device__ __forceinline__ float bf2f(u16 h) { return __uint_as_float(((u32)h) << 16); }

// bare v_exp_f32 (2^x). Inputs are bounded (|S| < ~4) so libm's range guards are dead
// weight; builtin (NOT inline asm) keeps hazard handling compiler-owned.
__device__ __forceinline__ float fexp2(float x) { return __builtin_amdgcn_exp2f(x); }

// truncation-pack two f32 -> packed bf16 pair via one v_perm_b32. Truncation bias
// cancelled by MFMA-computed softmax denominator over the SAME values.
__device__ __forceinline__ u32 pack_trunc(float lo, float hi) {
  return __builtin_amdgcn_perm(__float_as_uint(hi), __float_as_uint(lo), 0x07060302u);
}

__device__ __forceinline__ void gload16(const void* g, void* l) {
  __builtin_amdgcn_global_load_lds((const __attribute__((address_space(1))) void*)g,
                                   (__attribute__((address_space(3))) void*)l, 16, 0, 0);
}

// ---------------- fp32 -> bf16 convert, 3 tensors; first n4sb float4s of tensor b
// scaled by QSCALE (Wq = rows [0,768) of w_qkv = 768*768 floats = 147456 float4s) ------
__global__ __launch_bounds__(256) void cvt3_kernel(const float* __restrict__ a, u16* __restrict__ da, int n4a,
                                                   const float* __restrict__ b, u16* __restrict__ db, int n4b,
                                                   const float* __restrict__ c, u16* __restrict__ dc, int n4c,
                                                   int n4sb) {
  int i = blockIdx.x * 256 + threadIdx.x;
  const float* src;
  u16* dst;
  int n;
  float s = 1.0f;
  if (i < n4a) {
    src = a; dst = da; n = i;
  } else if (i < n4a + n4b) {
    src = b; dst = db; n = i - n4a;
    if (n < n4sb) s = QSCALE;
  } else if (i < n4a + n4b + n4c) {
    src = c; dst = dc; n = i - n4a - n4b;
  } else {
    return;
  }
  const float4 f = ((const float4*)src)[n];
  u16x4 o;
  o[0] = f2bf(f.x * s); o[1] = f2bf(f.y * s); o[2] = f2bf(f.z * s); o[3] = f2bf(f.w * s);
  ((u16x4*)dst)[n] = o;
}

// ---------------- 128x128 bf16 GEMM, C = A * B^T, 2-phase double-buffered ----------------
// BEST MEASURED CONFIG (r15: 52us/dispatch, SQ_LDS_BANK_CONFLICT=0). 4 waves x 64x64.
// Closed levers: depth-3 counted-vmcnt null (r8); depth-4 occupancy-negative (r12);
// 512-thr/8-wave regressed -10% (r16: 8-wave barrier join + worse L2 locality beat the
// TLP gain). LDS 16B-chunk XOR-swizzle sw(r)=(r>>1)&3, both-sides (pre-swizzled global
// source, linear gload_lds dest, swizzled ds_read).
// MODE 0: epilogue scatters qkv into q[B,H,N,64] (q pre-scaled via Wq), k[B,H,N,64], vT[B,H,64,N]
// MODE 1: epilogue writes fp32 out[M][N] += bias[n]; grid.x=136: [0,128) body+interact,
//   [128,136) head block-0-per-b, which ALSO broadcasts row 9 (vmean-proj) to rows 128..1023.
template <int MODE, int Mdim, int Ndim, int Kdim>
__global__ __launch_bounds__(256) void gemm_bt(const u16* __restrict__ A, const u16* __restrict__ Bw,
                                               u16* __restrict__ qb, u16* __restrict__ kb,
                                               u16* __restrict__ vTb,
                                               float* __restrict__ out, const float* __restrict__ bias) {
  __shared__ __align__(16) u16 lA[2][128 * 32];
  __shared__ __align__(16) u16 lB[2][128 * 32];
  __shared__ __align__(16) float bb[128];  // MODE-1 head-block broadcast row
  const int tid = threadIdx.x;
  const int wid = tid >> 6, lane = tid & 63;
  int m0;
  if constexpr (MODE == 1) {
    const int mb = blockIdx.x;
    m0 = (mb < 128) ? (8192 + mb * 128) : ((mb - 128) * 1024);
  } else {
    m0 = blockIdx.x * 128;
  }
  const int n0 = blockIdx.y * 128;
  const int wm = (wid >> 1) * 64, wn = (wid & 1) * 64;
  const int g = lane >> 4, r16 = lane & 15;

  f32x4 acc[4][4] = {};

  const int srow = wid * 16 + (lane >> 2);
  // pre-swizzled source chunk: LDS slot s=lane&3 of row srow receives global chunk s^sw(srow)
  const int scol = ((lane & 3) ^ ((srow >> 1) & 3)) * 8;
  const u16* gA = A + (size_t)(m0 + srow) * Kdim + scol;
  const u16* gB = Bw + (size_t)(n0 + srow) * Kdim + scol;

  // prologue: stage k0=0 into buffer 0
  gload16(gA, lA[0] + wid * 512);
  gload16(gA + (size_t)64 * Kdim, lA[0] + wid * 512 + 2048);
  gload16(gB, lB[0] + wid * 512);
  gload16(gB + (size_t)64 * Kdim, lB[0] + wid * 512 + 2048);
  __syncthreads();  // implicit vmcnt(0) drain

  int cur = 0;
  for (int k0 = 0; k0 < Kdim; k0 += 32) {
    if (k0 + 32 < Kdim) {  // prefetch next K-tile into the other buffer
      const int nk = k0 + 32;
      u16* lAn = lA[cur ^ 1] + wid * 512;
      u16* lBn = lB[cur ^ 1] + wid * 512;
      gload16(gA + nk, lAn);
      gload16(gA + (size_t)64 * Kdim + nk, lAn + 2048);
      gload16(gB + nk, lBn);
      gload16(gB + (size_t)64 * Kdim + nk, lBn + 2048);
    }
    const u16* lAc = lA[cur];
    const u16* lBc = lB[cur];
    bf16x8 af[4], bfr[4];
#pragma unroll
    for (int i = 0; i < 4; ++i) {
      const int R = wm + i * 16 + r16;
      af[i] = *(const bf16x8*)(lAc + R * 32 + ((g ^ ((R >> 1) & 3)) * 8));
    }
#pragma unroll
    for (int j = 0; j < 4; ++j) {
      const int R = wn + j * 16 + r16;
      bfr[j] = *(const bf16x8*)(lBc + R * 32 + ((g ^ ((R >> 1) & 3)) * 8));
    }
#pragma unroll
    for (int i = 0; i < 4; ++i)
#pragma unroll
      for (int j = 0; j < 4; ++j)
        acc[i][j] = __builtin_amdgcn_mfma_f32_16x16x32_bf16(af[i], bfr[j], acc[i][j], 0, 0, 0);
    __syncthreads();  // drains this iter's prefetch + all waves' ds_reads of cur
    cur ^= 1;
  }

#pragma unroll
  for (int i = 0; i < 4; ++i) {
    const int gm = m0 + wm + i * 16 + g * 4;  // multiple of 4
#pragma unroll
    for (int j = 0; j < 4; ++j) {
      const int gn = n0 + wn + j * 16 + r16;
      if constexpr (MODE == 1) {
        const float bv = bias[gn];
#pragma unroll
        for (int r = 0; r < 4; ++r) out[(size_t)(gm + r) * Ndim + gn] = acc[i][j][r] + bv;
      } else {
        const int t = gn / 768;
        const int rem = gn - t * 768;
        const int h = rem >> 6, d = rem & 63;
        if (t == 2) {
          // vT[b*12+h][d][n], 4 consecutive n -> one 8B store
          u16x4 pk;
#pragma unroll
          for (int r = 0; r < 4; ++r) pk[r] = f2bf(acc[i][j][r]);
          const int b = gm >> 10, n = gm & 1023;
          *(u16x4*)(vTb + ((size_t)((b * 12 + h) * 64 + d)) * 1024 + n) = pk;
        } else {
          u16* dst = (t == 0) ? qb : kb;
#pragma unroll
          for (int r = 0; r < 4; ++r) {
            const int b = (gm + r) >> 10, n = (gm + r) & 1023;
            dst[((size_t)((b * 12 + h) * 1024 + n)) * 64 + d] = f2bf(acc[i][j][r]);
          }
        }
      }
    }
  }

  if constexpr (MODE == 1) {
    // head blocks: broadcast row b*1024+9 (vmean projection) to rows 128..1023.
    // Row 9 = wm 0 (wid<2), i=0, g=2, r=1; value acc[0][j][1] + bias.
    if (blockIdx.x >= 128) {
      if (wid < 2 && g == 2) {
#pragma unroll
        for (int j = 0; j < 4; ++j) {
          const int col = wn + j * 16 + r16;
          bb[col] = acc[0][j][1] + bias[n0 + col];
        }
      }
      __syncthreads();  // block-uniform branch: all 256 threads participate
      const int b = blockIdx.x - 128;
      const float4 v = *(const float4*)&bb[(tid & 31) * 4];
      float* dst0 = out + (size_t)(b * 1024 + 128 + (tid >> 5)) * 768 + n0 + (tid & 31) * 4;
#pragma unroll 4
      for (int rr = 0; rr < 896; rr += 8)
        *(float4*)(dst0 + (size_t)rr * 768) = v;
    }
  }
}

// ---------------- per-(b,h) mean of v over tokens ----------------
__global__ __launch_bounds__(256) void vmean_kernel(const u16* __restrict__ vTb,
                                                    float* __restrict__ vmean) {
  const int bh = blockIdx.x, t = threadIdx.x;
  const int d = t >> 2, part = t & 3;
  const u16* src = vTb + ((size_t)bh * 64 + d) * 1024 + part * 256;
  float s = 0.f;
  for (int j = 0; j < 256; j += 8) {
    u16x8 u = *(const u16x8*)(src + j);
#pragma unroll
    for (int e = 0; e < 8; ++e) s += bf2f(u[e]);
  }
  s += __shfl_xor(s, 1);
  s += __shfl_xor(s, 2);
  if (part == 0) vmean[bh * 64 + d] = s * (1.0f / 1024.0f);
}

// ---------------- main body-branch attention (also computes interact rows 0..8) ----------
// ROUND-7 PROVEN SYNC SKELETON with TWO 64-row Q-groups per staged K/V chunk (round 13:
// stage+barrier complex amortized 2x; bk/bv fragments read once, used by both groups).
// Grid 768 = 3 blocks/CU. Swapped QK^T: S' = mfma(K_frag, Q_frag) -> S'[key][query];
// P truncation-packed (1 v_perm_b32/pair) into row-major P[query][key] (144B stride);
// PV A-frag = plain ds_read_b128; softmax denominator via ones-row MFMA over the SAME P.
__global__ __launch_bounds__(256) void body_attn(const u16* __restrict__ qg, const u16* __restrict__ kg,
                                                 const u16* __restrict__ vg, const float* __restrict__ vmean,
                                                 u16* __restrict__ og) {
  __shared__ __align__(16) u16 lK[2][64 * 64];   // [key][hd], 16B chunks XOR-swizzled by key&7
  __shared__ __align__(16) u16 lV[2][64 * 64];   // [d][tok64], 16B chunks XOR-swizzled by d&7
  __shared__ __align__(16) u16 lPA[4][16 * 72];  // per-wave P (group A), 144B row stride
  __shared__ __align__(16) u16 lPB[4][16 * 72];  // per-wave P (group B)

  const int blk = blockIdx.x;
  const int gid = (blk & 7) * 96 + (blk >> 3);  // XCD-chunked (768 % 8 == 0: bijective)
  const int rt2 = gid & 7, bh = gid >> 3;
  const int tid = threadIdx.x, wid = tid >> 6, lane = tid & 63;
  const int g = lane >> 4, r16 = lane & 15;
  const int rowA = rt2 * 128 + wid * 16;
  const int rowB = rowA + 64;

  const u16* qrowA = qg + ((size_t)bh * 1024 + rowA + r16) * 64;
  const u16* qrowB = qg + ((size_t)bh * 1024 + rowB + r16) * 64;
  const bf16x8 aqA0 = *(const bf16x8*)(qrowA + g * 8);
  const bf16x8 aqA1 = *(const bf16x8*)(qrowA + 32 + g * 8);
  const bf16x8 aqB0 = *(const bf16x8*)(qrowB + g * 8);
  const bf16x8 aqB1 = *(const bf16x8*)(qrowB + 32 + g * 8);

  const int lrow = lane >> 3, lch = lane & 7;
  const int swz = (lch ^ lrow) * 8;
  const int j0 = wid * 2;
  const u16* gK = kg + (size_t)bh * 65536 + (size_t)(j0 * 8 + lrow) * 64 + swz;
  const u16* gV = vg + (size_t)bh * 65536 + (size_t)(j0 * 8 + lrow) * 1024 + swz;

  f32x4 oaA[4] = {}, oaB[4] = {};
  f32x4 osumA = {}, osumB = {};
  u16* lPAw = lPA[wid];
  u16* lPBw = lPB[wid];

  bf16x8 vones;
#pragma unroll
  for (int i = 0; i < 8; ++i) vones[i] = (short)0x3F80;  // bf16 1.0

  auto stage = [&](int c0, int buf) {
    gload16(gK + (size_t)c0 * 64, lK[buf] + j0 * 512);
    gload16(gK + (size_t)c0 * 64 + 512, lK[buf] + (j0 + 1) * 512);
    gload16(gV + c0, lV[buf] + j0 * 512);
    gload16(gV + c0 + 8192, lV[buf] + (j0 + 1) * 512);
  };

  auto compute = [&](const u16* lKc, const u16* lVc, int c0) {
#pragma unroll
    for (int kt = 0; kt < 4; ++kt) {
      const int key = kt * 16 + r16;
      const bf16x8 bk0 = *(const bf16x8*)(lKc + key * 64 + ((g ^ (key & 7)) * 8));
      const bf16x8 bk1 = *(const bf16x8*)(lKc + key * 64 + (((4 + g) ^ (key & 7)) * 8));
      f32x4 SA = {}, SB = {};
      SA = __builtin_amdgcn_mfma_f32_16x16x32_bf16(bk0, aqA0, SA, 0, 0, 0);  // S'[key][query]
      SA = __builtin_amdgcn_mfma_f32_16x16x32_bf16(bk1, aqA1, SA, 0, 0, 0);
      SB = __builtin_amdgcn_mfma_f32_16x16x32_bf16(bk0, aqB0, SB, 0, 0, 0);
      SB = __builtin_amdgcn_mfma_f32_16x16x32_bf16(bk1, aqB1, SB, 0, 0, 0);
      float pA[4], pB[4];
#pragma unroll
      for (int r = 0; r < 4; ++r) { pA[r] = fexp2(SA[r]); pB[r] = fexp2(SB[r]); }
      if (c0 == 0 && kt == 0) {
        const int qA = rowA + r16;
        const bool dropA = (qA >= 1 && qA <= 8);  // interact rows 1..8: keys >= 9 only
#pragma unroll
        for (int r = 0; r < 4; ++r) {
          const int k = 4 * g + r;
          pA[r] = ((k >= 9) || (k == 0 && !dropA)) ? pA[r] : 0.f;
          pB[r] = ((k >= 9) || (k == 0)) ? pB[r] : 0.f;  // rowB >= 64: never drops k0
        }
      }
      u32x2 wA, wB;
      wA[0] = pack_trunc(pA[0], pA[1]);
      wA[1] = pack_trunc(pA[2], pA[3]);
      wB[0] = pack_trunc(pB[0], pB[1]);
      wB[1] = pack_trunc(pB[2], pB[3]);
      *(u32x2*)((char*)lPAw + r16 * 144 + kt * 32 + g * 8) = wA;
      *(u32x2*)((char*)lPBw + r16 * 144 + kt * 32 + g * 8) = wB;
    }
#pragma unroll
    for (int m = 0; m < 2; ++m) {
      const bf16x8 apA = *(const bf16x8*)((char*)lPAw + r16 * 144 + m * 64 + g * 16);
      const bf16x8 apB = *(const bf16x8*)((char*)lPBw + r16 * 144 + m * 64 + g * 16);
#pragma unroll
      for (int jt = 0; jt < 4; ++jt) {
        const int d = jt * 16 + r16;
        const bf16x8 bv = *(const bf16x8*)(lVc + d * 64 + (((m * 4 + g) ^ (d & 7)) * 8));
        oaA[jt] = __builtin_amdgcn_mfma_f32_16x16x32_bf16(apA, bv, oaA[jt], 0, 0, 0);
        oaB[jt] = __builtin_amdgcn_mfma_f32_16x16x32_bf16(apB, bv, oaB[jt], 0, 0, 0);
      }
      osumA = __builtin_amdgcn_mfma_f32_16x16x32_bf16(apA, vones, osumA, 0, 0, 0);
      osumB = __builtin_amdgcn_mfma_f32_16x16x32_bf16(apB, vones, osumB, 0, 0, 0);
    }
  };

  // prologue: stage chunk 0 into buffer 0
  stage(0, 0);
  __syncthreads();

  for (int it = 0; it < 8; ++it) {
    const int c0 = it * 128;
    stage(c0 + 64, 1);               // prefetch odd chunk into buf1
    compute(lK[0], lV[0], c0);
    __syncthreads();                 // buf1 ready; buf0 free
    if (it < 7) stage(c0 + 128, 0);  // prefetch next even chunk into buf0
    compute(lK[1], lV[1], c0 + 64);
    __syncthreads();                 // buf0 ready; buf1 free
  }

  const int b = bh / 12, h = bh - b * 12;
#pragma unroll
  for (int r = 0; r < 4; ++r) {
    // group A
    {
      const int grow = rowA + 4 * g + r;
      const bool full = (grow >= 1 && grow <= 8);
      const float inv = 1.f / osumA[r];
#pragma unroll
      for (int jt = 0; jt < 4; ++jt) {
        const int d = jt * 16 + r16;
        const float vi = oaA[jt][r] * inv;
        const float vb = full ? vmean[bh * 64 + d] : vi;
        og[((size_t)(8192 + b * 1024 + grow)) * 768 + h * 64 + d] = f2bf(vb);
        if (grow <= 8)  // interact rows 0..8 (only rt2==0, wid 0 reaches here)
          og[((size_t)(16384 + b * 1024 + grow)) * 768 + h * 64 + d] = f2bf(vi);
      }
    }
    // group B (rows >= 64: never "full", never interact-special)
    {
      const int grow = rowB + 4 * g + r;
      const float inv = 1.f / osumB[r];
#pragma unroll
      for (int jt = 0; jt < 4; ++jt) {
        const int d = jt * 16 + r16;
        og[((size_t)(8192 + b * 1024 + grow)) * 768 + h * 64 + d] = f2bf(oaB[jt][r] * inv);
      }
    }
  }
}

// ---------------- small branches (E path only) ----------------
// queries = 64 rows/block over all 1024 rows, keys [0,16) masked k<9.
//   grow < 9 : head rows 0..8 (computed)
//   grow >= 9: interact rows>=9 (computed) + head rows>=9 (vmean fill)
__global__ __launch_bounds__(256) void smalls_attn(const u16* __restrict__ qg, const u16* __restrict__ kg,
                                                   const u16* __restrict__ vg, const float* __restrict__ vmean,
                                                   u16* __restrict__ og) {
  __shared__ __align__(16) u16 lP2[4][16 * 40];  // per-wave P[query][key 0..31], 80B stride
  __shared__ float lsRed[4][16];
  const int bh = blockIdx.y;
  const int b = bh / 12, h = bh - b * 12;
  const int tid = threadIdx.x, wid = tid >> 6, lane = tid & 63;
  const int g = lane >> 4, r16 = lane & 15;
  u16* lPw = lP2[wid];

  const int row0 = blockIdx.x * 64 + wid * 16;
  const u16* qrow = qg + ((size_t)bh * 1024 + row0 + r16) * 64;
  const bf16x8 aq0 = *(const bf16x8*)(qrow + g * 8);
  const bf16x8 aq1 = *(const bf16x8*)(qrow + 32 + g * 8);
  const u16* krow = kg + ((size_t)bh * 1024 + r16) * 64;  // keys 0..15
  const bf16x8 bk0 = *(const bf16x8*)(krow + g * 8);
  const bf16x8 bk1 = *(const bf16x8*)(krow + 32 + g * 8);
  f32x4 S = {};
  S = __builtin_amdgcn_mfma_f32_16x16x32_bf16(bk0, aq0, S, 0, 0, 0);  // S'[key][query]
  S = __builtin_amdgcn_mfma_f32_16x16x32_bf16(bk1, aq1, S, 0, 0, 0);
  float p[4];
  float lsum = 0.f;
#pragma unroll
  for (int r = 0; r < 4; ++r) {
    const int k = 4 * g + r;
    p[r] = (k < 9) ? fexp2(S[r]) : 0.f;
    lsum += p[r];
  }
  {
    u16x4 pk;
#pragma unroll
    for (int r = 0; r < 4; ++r) pk[r] = f2bf(p[r]);
    *(u16x4*)((char*)lPw + r16 * 80 + g * 8) = pk;
    u16x4 z = {0, 0, 0, 0};
    *(u16x4*)((char*)lPw + r16 * 80 + 32 + g * 8) = z;  // keys 16..31 = 0
  }
  lsum += __shfl_xor(lsum, 16);
  lsum += __shfl_xor(lsum, 32);
  if (lane < 16) lsRed[wid][lane] = lsum;
  const bf16x8 ap = *(const bf16x8*)((char*)lPw + r16 * 80 + g * 16);
  f32x4 oa[4] = {};
#pragma unroll
  for (int jt = 0; jt < 4; ++jt) {
    const u16* vrow = vg + ((size_t)bh * 64 + jt * 16 + r16) * 1024;  // tokens 0..31
    const bf16x8 bv = *(const bf16x8*)(vrow + g * 8);
    oa[jt] = __builtin_amdgcn_mfma_f32_16x16x32_bf16(ap, bv, oa[jt], 0, 0, 0);
  }
#pragma unroll
  for (int r = 0; r < 4; ++r) {
    const int grow = row0 + 4 * g + r;
    const float inv = 1.f / lsRed[wid][4 * g + r];
#pragma unroll
    for (int jt = 0; jt < 4; ++jt) {
      const int d = jt * 16 + r16;
      const float v = oa[jt][r] * inv;
      if (grow >= 9) {
        og[((size_t)(16384 + b * 1024 + grow)) * 768 + h * 64 + d] = f2bf(v);          // interact
        og[((size_t)(b * 1024 + grow)) * 768 + h * 64 + d] = f2bf(vmean[bh * 64 + d]); // head fill
      } else {
        og[((size_t)(b * 1024 + grow)) * 768 + h * 64 + d] = f2bf(v);                  // head 0..8
      }
    }
  }
}

// ---------------- host launcher ----------------
extern "C" void kernel_launch(void* const* d_in, const int* in_sizes, int n_in,
                              void* d_out, int out_size, void* d_ws, size_t ws_size,
                              hipStream_t stream) {
  (void)in_sizes; (void)n_in; (void)out_size; (void)ws_size;
  const float* x      = (const float*)d_in[0];
  const float* w_qkv  = (const float*)d_in[1];
  const float* w_proj = (const float*)d_in[2];
  const float* b_proj = (const float*)d_in[3];

  char* ws = (char*)d_ws;
  u16* xb     = (u16*)(ws + 0);
  u16* wqkvb  = (u16*)(ws + 12582912);
  u16* wprojb = (u16*)(ws + 16121856);
  u16* qb     = (u16*)(ws + 17301504);
  u16* kb     = (u16*)(ws + 29884416);
  u16* vTb    = (u16*)(ws + 42467328);
  float* vmn  = (float*)(ws + 55050240);
  u16* ob     = (u16*)(ws + 55074816);

  // Wq = rows [0,768) of w_qkv = 768*768 floats = 147456 float4s: pre-scaled by QSCALE.
  cvt3_kernel<<<8449, 256, 0, stream>>>(x, xb, 1572864, w_qkv, wqkvb, 442368,
                                        w_proj, wprojb, 147456, 147456);

  gemm_bt<0, 8192, 2304, 768><<<dim3(64, 18), 256, 0, stream>>>(
      xb, wqkvb, qb, kb, vTb, nullptr, nullptr);

  vmean_kernel<<<96, 256, 0, stream>>>(vTb, vmn);

  body_attn<<<768, 256, 0, stream>>>(qb, kb, vTb, vmn, ob);
  smalls_attn<<<dim3(16, 96), 256, 0, stream>>>(qb, kb, vTb, vmn, ob);

  gemm_bt<1, 24576, 768, 768><<<dim3(136, 6), 256, 0, stream>>>(
      ob, wprojb, nullptr, nullptr, nullptr, (float*)d_out, b_proj);
}